// Round 1
// baseline (308.589 us; speedup 1.0000x reference)
//
#include <hip/hip_runtime.h>
#include <stdint.h>

#define NLVL 16
#define TSIZE 16384
#define HW 512

__constant__ int c_n[NLVL] = {16,20,25,32,40,50,64,80,101,128,161,203,256,322,406,512};
__constant__ int c_k[NLVL] = {32,25,20,16,12,10, 8, 6,  5,  4,  3,  2,  2,  1,  1,  1};

__device__ __forceinline__ uint32_t pkmax(uint32_t a, uint32_t b) {
    uint32_t r;
    asm("v_pk_max_u16 %0, %1, %2" : "=v"(r) : "v"(a), "v"(b));
    return r;
}

// Kernel 1: per (level, batch, 32x32 tile of the pooled grid):
//   load x region (<=63x63), trunc(x*n) per channel, pack 2 channels into u32,
//   separable max-pool in LDS (row-max then col-max), hash, store u16 idx grid.
__global__ __launch_bounds__(256) void pool_hash_kernel(
        const float* __restrict__ x, uint16_t* __restrict__ idxws) {
    __shared__ uint32_t gbuf[63][65];  // packed g values, padded stride (bank-safe)
    __shared__ uint32_t rbuf[63][33];  // row-max results
    const int lvl = blockIdx.z >> 3;
    const int b   = blockIdx.z & 7;
    const int k   = c_k[lvl];
    const int gh  = 513 - k;           // == gw
    const int gy0 = blockIdx.y * 32;
    const int gx0 = blockIdx.x * 32;
    if (gy0 >= gh) return;
    const float nf = (float)c_n[lvl];
    const int R = 31 + k;              // region rows == cols (<=63)
    const int tid = threadIdx.x;
    const float* xb0 = x + (size_t)b * 2 * HW * HW;
    const float* xb1 = xb0 + HW * HW;

    // ---- load + trunc + pack (threads as 4 rows x 64 cols) ----
    {
        const int lr = tid >> 6, lc = tid & 63;
        if (lc < R) {
            int xx = gx0 + lc; if (xx > HW - 1) xx = HW - 1;
            for (int r = lr; r < R; r += 4) {
                int yy = gy0 + r; if (yy > HW - 1) yy = HW - 1;
                float v0 = xb0[yy * HW + xx];
                float v1 = xb1[yy * HW + xx];
                uint32_t p = (uint32_t)(v0 * nf) | ((uint32_t)(v1 * nf) << 16);
                gbuf[r][lc] = p;
            }
        }
    }
    __syncthreads();

    const int ty = tid >> 5, tx = tid & 31;
    // ---- row max (window k, stride 1) ----
    for (int r = ty; r < R; r += 8) {
        uint32_t m = gbuf[r][tx];
        for (int j = 1; j < k; ++j) m = pkmax(m, gbuf[r][tx + j]);
        rbuf[r][tx] = m;
    }
    __syncthreads();

    // ---- col max + hash + store ----
    uint16_t* og = idxws + (size_t)(lvl * 8 + b) * HW * HW;
    const int gx = gx0 + tx;
    if (gx < gh) {
        for (int oy = ty; oy < 32; oy += 8) {
            const int gy = gy0 + oy;
            if (gy >= gh) continue;
            uint32_t m = rbuf[oy][tx];
            for (int j = 1; j < k; ++j) m = pkmax(m, rbuf[oy + j][tx]);
            uint32_t g0 = m & 0xFFFFu, g1 = m >> 16;
            uint32_t idx = (g0 ^ (g1 * 2654435761u)) & (TSIZE - 1);
            og[gy * HW + gx] = (uint16_t)idx;
        }
    }
}

// Kernel 2: per (level, batch, y, x): half-pixel-center bilinear sample of the
// gathered hash features; writes 2 channels.
__global__ __launch_bounds__(256) void upsample_kernel(
        const uint16_t* __restrict__ idxws, const float* __restrict__ table,
        float* __restrict__ out) {
    const int lvl = blockIdx.z >> 3;
    const int b   = blockIdx.z & 7;
    const int y   = blockIdx.y;
    const int xo  = blockIdx.x * 256 + threadIdx.x;
    const int gh  = 513 - c_k[lvl];
    const float scale = (float)gh * (1.0f / 512.0f);

    float sy = ((float)y + 0.5f) * scale - 0.5f;
    float fy = floorf(sy);
    float wy = sy - fy;
    int y0 = (int)fy, y1 = y0 + 1;
    y0 = max(y0, 0); y1 = min(y1, gh - 1);

    float sx = ((float)xo + 0.5f) * scale - 0.5f;
    float fx = floorf(sx);
    float wx = sx - fx;
    int x0 = (int)fx, x1 = x0 + 1;
    x0 = max(x0, 0); x1 = min(x1, gh - 1);

    const uint16_t* ig = idxws + (size_t)(lvl * 8 + b) * HW * HW;
    const int r0 = y0 * HW, r1 = y1 * HW;
    uint32_t i00 = ig[r0 + x0], i01 = ig[r0 + x1];
    uint32_t i10 = ig[r1 + x0], i11 = ig[r1 + x1];

    const float2* tb = (const float2*)table + (size_t)lvl * TSIZE;
    float2 f00 = tb[i00], f01 = tb[i01], f10 = tb[i10], f11 = tb[i11];

    float w11 = wy * wx;
    float w10 = wy - w11;
    float w01 = wx - w11;
    float w00 = 1.0f - wy - wx + w11;
    float c0 = f00.x * w00 + f01.x * w01 + f10.x * w10 + f11.x * w11;
    float c1 = f00.y * w00 + f01.y * w01 + f10.y * w10 + f11.y * w11;

    size_t o0 = (((size_t)b * 32 + lvl * 2) * HW + y) * HW + xo;
    out[o0] = c0;
    out[o0 + (size_t)HW * HW] = c1;
}

extern "C" void kernel_launch(void* const* d_in, const int* in_sizes, int n_in,
                              void* d_out, int out_size, void* d_ws, size_t ws_size,
                              hipStream_t stream) {
    const float* x     = (const float*)d_in[0];
    const float* table = (const float*)d_in[1];
    float* out         = (float*)d_out;
    uint16_t* idxws    = (uint16_t*)d_ws;

    // need 16 levels * 8 batch * 512*512 u16 = 64 MiB scratch
    if (ws_size < (size_t)NLVL * 8 * HW * HW * sizeof(uint16_t)) return;

    dim3 blk(256);
    pool_hash_kernel<<<dim3(16, 16, NLVL * 8), blk, 0, stream>>>(x, idxws);
    upsample_kernel<<<dim3(2, HW, NLVL * 8), blk, 0, stream>>>(idxws, table, out);
}

// Round 2
// 254.296 us; speedup vs baseline: 1.2135x; 1.2135x over previous
//
#include <hip/hip_runtime.h>
#include <stdint.h>

#define NLVL 16
#define TSIZE 16384
#define HW 512

__constant__ int c_n[NLVL] = {16,20,25,32,40,50,64,80,101,128,161,203,256,322,406,512};
__constant__ int c_k[NLVL] = {32,25,20,16,12,10, 8, 6,  5,  4,  3,  2,  2,  1,  1,  1};

__device__ __forceinline__ uint32_t pkmax(uint32_t a, uint32_t b) {
    uint32_t r;
    asm("v_pk_max_u16 %0, %1, %2" : "=v"(r) : "v"(a), "v"(b));
    return r;
}

// One block = one (level, batch, 32x32 output tile).
// Phases: load+trunc+pack -> row-max -> col-max+hash+gather -> bilerp+store.
__global__ __launch_bounds__(256) void fused_kernel(
        const float* __restrict__ x, const float* __restrict__ table,
        float* __restrict__ out) {
    __shared__ __align__(16) uint32_t gbuf[64][65];  // packed inputs; reused as feat
    __shared__ uint32_t rbuf[64][34];                // row-max results
    float2 (*feat)[34] = (float2(*)[34])&gbuf[0][0]; // 33*34*8 = 8976 B <= 16640 B

    const int lvl = blockIdx.z >> 3;
    const int b   = blockIdx.z & 7;
    const int k   = c_k[lvl];
    const int gh  = 513 - k;                 // pooled grid is gh x gh
    const int ty0 = blockIdx.y * 32;
    const int tx0 = blockIdx.x * 32;
    const float s  = (float)gh * (1.0f / 512.0f);   // exact (gh * 2^-9)
    const float nf = (float)c_n[lvl];
    const int tid = threadIdx.x;

    // grid-coordinate window for this tile (half-pixel centers)
    const int gy_base = (int)floorf(((float)ty0 + 0.5f) * s - 0.5f);  // may be -1
    const int gx_base = (int)floorf(((float)tx0 + 0.5f) * s - 0.5f);
    const int rmin = max(gy_base, 0);
    const int rmax = min(gy_base + 32, gh - 1);
    const int cmin = max(gx_base, 0);
    const int cmax = min(gx_base + 32, gh - 1);
    const int Rr = rmax - rmin + k;          // input rows needed (<=64)
    const int Rc = cmax - cmin + k;          // input cols needed (<=64)

    const float* xb0 = x + (size_t)b * 2 * HW * HW;
    const float* xb1 = xb0 + HW * HW;

    // ---- phase 1: load + trunc + pack both channels into u32 ----
    {
        const int lr = tid >> 6, lc = tid & 63;
        if (lc < Rc) {
            const int xx = cmin + lc;        // always within [0, 511]
            for (int r = lr; r < Rr; r += 4) {
                const int yy = rmin + r;     // always within [0, 511]
                float v0 = xb0[yy * HW + xx];
                float v1 = xb1[yy * HW + xx];
                gbuf[r][lc] = (uint32_t)(v0 * nf) | ((uint32_t)(v1 * nf) << 16);
            }
        }
    }
    __syncthreads();

    // ---- phase 2: horizontal max (window k) for 33 grid cols ----
    for (int p = tid; p < Rr * 33; p += 256) {
        const int r = p / 33, j = p - r * 33;
        const int cj = min(max(gx_base + j, 0), gh - 1) - cmin;
        uint32_t m = gbuf[r][cj];
        for (int t = 1; t < k; ++t) m = pkmax(m, gbuf[r][cj + t]);
        rbuf[r][j] = m;
    }
    __syncthreads();

    // ---- phase 3: vertical max + hash + table gather into feat ----
    const float2* tb = (const float2*)table + (size_t)lvl * TSIZE;
    for (int p = tid; p < 33 * 33; p += 256) {
        const int i = p / 33, j = p - i * 33;
        const int ri = min(max(gy_base + i, 0), gh - 1) - rmin;
        uint32_t m = rbuf[ri][j];
        for (int t = 1; t < k; ++t) m = pkmax(m, rbuf[ri + t][j]);
        const uint32_t g0 = m & 0xFFFFu, g1 = m >> 16;
        const uint32_t idx = (g0 ^ (g1 * 2654435761u)) & (TSIZE - 1);
        feat[i][j] = tb[idx];
    }
    __syncthreads();

    // ---- phase 4: bilinear interp from LDS + store ----
    const int bty = tid >> 5, btx = tid & 31;
    const int xo = tx0 + btx;
    const float sxf = ((float)xo + 0.5f) * s - 0.5f;
    const float fxf = floorf(sxf);
    const float wx = sxf - fxf;
    const int jx = (int)fxf - gx_base;       // in [0, 31]
    float* ob = out + ((size_t)b * 32 + lvl * 2) * HW * HW;
    for (int oy = bty; oy < 32; oy += 8) {
        const int y = ty0 + oy;
        const float syf = ((float)y + 0.5f) * s - 0.5f;
        const float fyf = floorf(syf);
        const float wy = syf - fyf;
        const int iy = (int)fyf - gy_base;   // in [0, 31]
        const float2 f00 = feat[iy][jx],     f01 = feat[iy][jx + 1];
        const float2 f10 = feat[iy + 1][jx], f11 = feat[iy + 1][jx + 1];
        const float w11 = wy * wx;
        const float w10 = wy - w11;
        const float w01 = wx - w11;
        const float w00 = 1.0f - wy - wx + w11;
        const float c0 = f00.x * w00 + f01.x * w01 + f10.x * w10 + f11.x * w11;
        const float c1 = f00.y * w00 + f01.y * w01 + f10.y * w10 + f11.y * w11;
        const size_t o = (size_t)y * HW + xo;
        ob[o] = c0;
        ob[o + (size_t)HW * HW] = c1;
    }
}

extern "C" void kernel_launch(void* const* d_in, const int* in_sizes, int n_in,
                              void* d_out, int out_size, void* d_ws, size_t ws_size,
                              hipStream_t stream) {
    const float* x     = (const float*)d_in[0];
    const float* table = (const float*)d_in[1];
    float* out         = (float*)d_out;
    (void)d_ws; (void)ws_size;

    fused_kernel<<<dim3(16, 16, NLVL * 8), dim3(256), 0, stream>>>(x, table, out);
}

// Round 3
// 234.879 us; speedup vs baseline: 1.3138x; 1.0827x over previous
//
#include <hip/hip_runtime.h>
#include <stdint.h>

#define NLVL 16
#define TSIZE 16384
#define HW 512

__constant__ int c_n[NLVL] = {16,20,25,32,40,50,64,80,101,128,161,203,256,322,406,512};
__constant__ int c_k[NLVL] = {32,25,20,16,12,10, 8, 6,  5,  4,  3,  2,  2,  1,  1,  1};

__device__ __forceinline__ uint32_t pkmax(uint32_t a, uint32_t b) {
    uint32_t r;
    asm("v_pk_max_u16 %0, %1, %2" : "=v"(r) : "v"(a), "v"(b));
    return r;
}

// One block = one (level, batch, 32x32 output tile), flat 1D grid remapped so
// that batch == blockIdx.x % 8  ->  each XCD (round-robin dispatch) serves ONE
// batch; that batch's x (2 MB) + all hash tables (2 MB) fit the 4 MiB per-XCD
// L2. Output is stored nontemporally to avoid evicting them.
__global__ __launch_bounds__(256) void fused_kernel(
        const float* __restrict__ x, const float* __restrict__ table,
        float* __restrict__ out) {
    __shared__ __align__(16) uint32_t gbuf[64][65];  // packed inputs; reused as feat
    __shared__ uint32_t rbuf[64][34];                // row-max results
    float2 (*feat)[34] = (float2(*)[34])&gbuf[0][0]; // 33*34*8 = 8976 B fits

    const int bid  = blockIdx.x;
    const int b    = bid & 7;            // fastest -> pins batch to XCD
    const int lvl  = (bid >> 3) & 15;
    const int tile = bid >> 7;           // 0..255
    const int tx0  = (tile & 15) * 32;
    const int ty0  = (tile >> 4) * 32;

    const int k   = c_k[lvl];
    const int gh  = 513 - k;                 // pooled grid is gh x gh
    const float s  = (float)gh * (1.0f / 512.0f);   // exact (gh * 2^-9)
    const float nf = (float)c_n[lvl];
    const int tid = threadIdx.x;

    // grid-coordinate window for this tile (half-pixel centers)
    const int gy_base = (int)floorf(((float)ty0 + 0.5f) * s - 0.5f);  // may be -1
    const int gx_base = (int)floorf(((float)tx0 + 0.5f) * s - 0.5f);
    const int rmin = max(gy_base, 0);
    const int rmax = min(gy_base + 32, gh - 1);
    const int cmin = max(gx_base, 0);
    const int cmax = min(gx_base + 32, gh - 1);
    const int Rr = rmax - rmin + k;          // input rows needed (<=64)
    const int Rc = cmax - cmin + k;          // input cols needed (<=64)

    const float* xb0 = x + (size_t)b * 2 * HW * HW;
    const float* xb1 = xb0 + HW * HW;

    // ---- phase 1: load + trunc + pack both channels into u32 ----
    {
        const int lr = tid >> 6, lc = tid & 63;
        if (lc < Rc) {
            const int xx = cmin + lc;        // within [0, 511]
            for (int r = lr; r < Rr; r += 4) {
                const int yy = rmin + r;     // within [0, 511]
                float v0 = xb0[yy * HW + xx];
                float v1 = xb1[yy * HW + xx];
                gbuf[r][lc] = (uint32_t)(v0 * nf) | ((uint32_t)(v1 * nf) << 16);
            }
        }
    }
    __syncthreads();

    // ---- phase 2: horizontal max (window k) for 33 grid cols ----
    {
        // j in [0,32): 32 cols x 8 row-stride
        const int j = tid & 31;
        const int cj = min(max(gx_base + j, 0), gh - 1) - cmin;
        for (int r = tid >> 5; r < Rr; r += 8) {
            uint32_t m = gbuf[r][cj];
            for (int t = 1; t < k; ++t) m = pkmax(m, gbuf[r][cj + t]);
            rbuf[r][j] = m;
        }
        // j == 32 column: one row per thread
        if (tid < Rr) {
            const int cj32 = min(max(gx_base + 32, 0), gh - 1) - cmin;
            uint32_t m = gbuf[tid][cj32];
            for (int t = 1; t < k; ++t) m = pkmax(m, gbuf[tid][cj32 + t]);
            rbuf[tid][32] = m;
        }
    }
    __syncthreads();

    // ---- phase 3: vertical max + hash + table gather into feat ----
    const float2* tb = (const float2*)table + (size_t)lvl * TSIZE;
    {
        const int j = tid & 31;
        for (int i = tid >> 5; i < 33; i += 8) {
            const int ri = min(max(gy_base + i, 0), gh - 1) - rmin;
            uint32_t m = rbuf[ri][j];
            for (int t = 1; t < k; ++t) m = pkmax(m, rbuf[ri + t][j]);
            const uint32_t idx = ((m & 0xFFFFu) ^ ((m >> 16) * 2654435761u)) & (TSIZE - 1);
            feat[i][j] = tb[idx];
        }
        if (tid < 33) {                      // j == 32 column
            const int ri = min(max(gy_base + tid, 0), gh - 1) - rmin;
            uint32_t m = rbuf[ri][32];
            for (int t = 1; t < k; ++t) m = pkmax(m, rbuf[ri + t][32]);
            const uint32_t idx = ((m & 0xFFFFu) ^ ((m >> 16) * 2654435761u)) & (TSIZE - 1);
            feat[tid][32] = tb[idx];
        }
    }
    __syncthreads();

    // ---- phase 4: bilinear interp from LDS + nontemporal store ----
    const int bty = tid >> 5, btx = tid & 31;
    const int xo = tx0 + btx;
    const float sxf = ((float)xo + 0.5f) * s - 0.5f;
    const float fxf = floorf(sxf);
    const float wx = sxf - fxf;
    const int jx = (int)fxf - gx_base;       // in [0, 31]
    float* ob = out + ((size_t)b * 32 + lvl * 2) * HW * HW;
    for (int oy = bty; oy < 32; oy += 8) {
        const int y = ty0 + oy;
        const float syf = ((float)y + 0.5f) * s - 0.5f;
        const float fyf = floorf(syf);
        const float wy = syf - fyf;
        const int iy = (int)fyf - gy_base;   // in [0, 31]
        const float2 f00 = feat[iy][jx],     f01 = feat[iy][jx + 1];
        const float2 f10 = feat[iy + 1][jx], f11 = feat[iy + 1][jx + 1];
        const float w11 = wy * wx;
        const float w10 = wy - w11;
        const float w01 = wx - w11;
        const float w00 = 1.0f - wy - wx + w11;
        const float c0 = f00.x * w00 + f01.x * w01 + f10.x * w10 + f11.x * w11;
        const float c1 = f00.y * w00 + f01.y * w01 + f10.y * w10 + f11.y * w11;
        const size_t o = (size_t)y * HW + xo;
        __builtin_nontemporal_store(c0, &ob[o]);
        __builtin_nontemporal_store(c1, &ob[o + (size_t)HW * HW]);
    }
}

extern "C" void kernel_launch(void* const* d_in, const int* in_sizes, int n_in,
                              void* d_out, int out_size, void* d_ws, size_t ws_size,
                              hipStream_t stream) {
    const float* x     = (const float*)d_in[0];
    const float* table = (const float*)d_in[1];
    float* out         = (float*)d_out;
    (void)d_ws; (void)ws_size;

    fused_kernel<<<dim3(16 * 16 * NLVL * 8), dim3(256), 0, stream>>>(x, table, out);
}

// Round 4
// 136.337 us; speedup vs baseline: 2.2634x; 1.7228x over previous
//
#include <hip/hip_runtime.h>
#include <stdint.h>

#define NLVL 16
#define TSIZE 16384
#define HW 512

__constant__ int c_n[NLVL] = {16,20,25,32,40,50,64,80,101,128,161,203,256,322,406,512};

__device__ __forceinline__ uint32_t pkmax(uint32_t a, uint32_t b) {
    uint32_t r;
    asm("v_pk_max_u16 %0, %1, %2" : "=v"(r) : "v"(a), "v"(b));
    return r;
}

// One block = one (level, batch, 32x32 output tile).
// K (pool window) is a compile-time template parameter -> pooling loops fully
// unroll, all K ds_reads issue back-to-back (latency amortized) instead of a
// serial read->wait->max chain per element.
template<int K>
__device__ __forceinline__ void do_tile(
        const int lvl, const int b, const int tx0, const int ty0,
        const float* __restrict__ x, const float* __restrict__ table,
        float* __restrict__ out,
        uint32_t (&gbuf)[64][65], uint32_t (&rbuf)[64][33]) {
    constexpr int gh = 513 - K;                       // pooled grid is gh x gh
    constexpr float s = (float)gh * (1.0f / 512.0f);  // exact (gh * 2^-9)
    const float nf = (float)c_n[lvl];
    const int tid = threadIdx.x;

    float2 (*feat)[34] = (float2(*)[34])&gbuf[0][0];  // aliases gbuf (dead after row-max)

    // grid-coordinate window for this tile (half-pixel centers)
    const int gy_base = (int)floorf(((float)ty0 + 0.5f) * s - 0.5f);  // may be -1
    const int gx_base = (int)floorf(((float)tx0 + 0.5f) * s - 0.5f);

    const float* xb0 = x + (size_t)b * 2 * HW * HW;
    const float* xb1 = xb0 + HW * HW;
    const float2* tb = (const float2*)table + (size_t)lvl * TSIZE;

    if constexpr (K == 1) {
        // gh == 512: pooled grid IS trunc(x*n); gather 33x33 feats directly.
        for (int p = tid; p < 33 * 33; p += 256) {
            const int i = p / 33, j = p - i * 33;
            const int yy = min(max(gy_base + i, 0), HW - 1);
            const int xx = min(max(gx_base + j, 0), HW - 1);
            const uint32_t g0 = (uint32_t)(xb0[yy * HW + xx] * nf);
            const uint32_t g1 = (uint32_t)(xb1[yy * HW + xx] * nf);
            const uint32_t idx = (g0 ^ (g1 * 2654435761u)) & (TSIZE - 1);
            feat[i][j] = tb[idx];
        }
        __syncthreads();
    } else {
        const int rmin = max(gy_base, 0);
        const int rmax = min(gy_base + 32, gh - 1);
        const int cmin = max(gx_base, 0);
        const int cmax = min(gx_base + 32, gh - 1);
        const int Rr = rmax - rmin + K;               // input rows needed (<=63)
        const int Rc = cmax - cmin + K;               // input cols needed (<=63)

        // ---- phase 1: load + trunc + pack both channels into u32 ----
        {
            const int lr = tid >> 6, lc = tid & 63;
            if (lc < Rc) {
                const int xx = cmin + lc;             // within [0, 511]
                for (int r = lr; r < Rr; r += 4) {
                    const int yy = rmin + r;          // within [0, 511]
                    const float v0 = xb0[yy * HW + xx];
                    const float v1 = xb1[yy * HW + xx];
                    gbuf[r][lc] = (uint32_t)(v0 * nf) | ((uint32_t)(v1 * nf) << 16);
                }
            }
        }
        __syncthreads();

        // ---- phase 2: horizontal max (window K, unrolled) for 33 grid cols ----
        {
            const int j = tid & 31;
            const int cj = min(max(gx_base + j, 0), gh - 1) - cmin;
            for (int r = tid >> 5; r < Rr; r += 8) {
                uint32_t m = gbuf[r][cj];
#pragma unroll
                for (int t = 1; t < K; ++t) m = pkmax(m, gbuf[r][cj + t]);
                rbuf[r][j] = m;
            }
            if (tid < Rr) {                           // j == 32 tail column
                const int cj32 = min(max(gx_base + 32, 0), gh - 1) - cmin;
                uint32_t m = gbuf[tid][cj32];
#pragma unroll
                for (int t = 1; t < K; ++t) m = pkmax(m, gbuf[tid][cj32 + t]);
                rbuf[tid][32] = m;
            }
        }
        __syncthreads();

        // ---- phase 3: vertical max (unrolled) + hash + gather into feat ----
        {
            const int j = tid & 31;
            for (int i = tid >> 5; i < 33; i += 8) {
                const int ri = min(max(gy_base + i, 0), gh - 1) - rmin;
                uint32_t m = rbuf[ri][j];
#pragma unroll
                for (int t = 1; t < K; ++t) m = pkmax(m, rbuf[ri + t][j]);
                const uint32_t idx = ((m & 0xFFFFu) ^ ((m >> 16) * 2654435761u)) & (TSIZE - 1);
                feat[i][j] = tb[idx];
            }
            if (tid < 33) {                           // j == 32 tail column
                const int ri = min(max(gy_base + tid, 0), gh - 1) - rmin;
                uint32_t m = rbuf[ri][32];
#pragma unroll
                for (int t = 1; t < K; ++t) m = pkmax(m, rbuf[ri + t][32]);
                const uint32_t idx = ((m & 0xFFFFu) ^ ((m >> 16) * 2654435761u)) & (TSIZE - 1);
                feat[tid][32] = tb[idx];
            }
        }
        __syncthreads();
    }

    // ---- phase 4: bilinear interp from LDS + nontemporal store ----
    const int bty = tid >> 5, btx = tid & 31;
    const int xo = tx0 + btx;
    const float sxf = ((float)xo + 0.5f) * s - 0.5f;
    const float fxf = floorf(sxf);
    const float wx = sxf - fxf;
    const int jx = (int)fxf - gx_base;                // in [0, 31]
    float* ob = out + ((size_t)b * 32 + lvl * 2) * HW * HW;
    for (int oy = bty; oy < 32; oy += 8) {
        const int y = ty0 + oy;
        const float syf = ((float)y + 0.5f) * s - 0.5f;
        const float fyf = floorf(syf);
        const float wy = syf - fyf;
        const int iy = (int)fyf - gy_base;            // in [0, 31]
        const float2 f00 = feat[iy][jx],     f01 = feat[iy][jx + 1];
        const float2 f10 = feat[iy + 1][jx], f11 = feat[iy + 1][jx + 1];
        const float w11 = wy * wx;
        const float w10 = wy - w11;
        const float w01 = wx - w11;
        const float w00 = 1.0f - wy - wx + w11;
        const float c0 = f00.x * w00 + f01.x * w01 + f10.x * w10 + f11.x * w11;
        const float c1 = f00.y * w00 + f01.y * w01 + f10.y * w10 + f11.y * w11;
        const size_t o = (size_t)y * HW + xo;
        __builtin_nontemporal_store(c0, &ob[o]);
        __builtin_nontemporal_store(c1, &ob[o + (size_t)HW * HW]);
    }
}

// Grid order: bid = lvl*2048 + tile*8 + b.
//  - b fastest  -> batch pinned to XCD (x slice + tables stay L2-resident)
//  - lvl slowest-> co-resident blocks on a CU share the same specialized code
//                  path (no I-cache thrash) and neighboring tiles (x overlap).
__global__ __launch_bounds__(256) void fused_kernel(
        const float* __restrict__ x, const float* __restrict__ table,
        float* __restrict__ out) {
    __shared__ __align__(16) uint32_t gbuf[64][65];
    __shared__ uint32_t rbuf[64][33];

    const int bid  = blockIdx.x;
    const int b    = bid & 7;
    const int tile = (bid >> 3) & 255;
    const int lvl  = bid >> 11;
    const int tx0  = (tile & 15) * 32;
    const int ty0  = (tile >> 4) * 32;

    switch (lvl) {
        case  0: do_tile<32>( 0, b, tx0, ty0, x, table, out, gbuf, rbuf); break;
        case  1: do_tile<25>( 1, b, tx0, ty0, x, table, out, gbuf, rbuf); break;
        case  2: do_tile<20>( 2, b, tx0, ty0, x, table, out, gbuf, rbuf); break;
        case  3: do_tile<16>( 3, b, tx0, ty0, x, table, out, gbuf, rbuf); break;
        case  4: do_tile<12>( 4, b, tx0, ty0, x, table, out, gbuf, rbuf); break;
        case  5: do_tile<10>( 5, b, tx0, ty0, x, table, out, gbuf, rbuf); break;
        case  6: do_tile< 8>( 6, b, tx0, ty0, x, table, out, gbuf, rbuf); break;
        case  7: do_tile< 6>( 7, b, tx0, ty0, x, table, out, gbuf, rbuf); break;
        case  8: do_tile< 5>( 8, b, tx0, ty0, x, table, out, gbuf, rbuf); break;
        case  9: do_tile< 4>( 9, b, tx0, ty0, x, table, out, gbuf, rbuf); break;
        case 10: do_tile< 3>(10, b, tx0, ty0, x, table, out, gbuf, rbuf); break;
        case 11: do_tile< 2>(11, b, tx0, ty0, x, table, out, gbuf, rbuf); break;
        case 12: do_tile< 2>(12, b, tx0, ty0, x, table, out, gbuf, rbuf); break;
        case 13: do_tile< 1>(13, b, tx0, ty0, x, table, out, gbuf, rbuf); break;
        case 14: do_tile< 1>(14, b, tx0, ty0, x, table, out, gbuf, rbuf); break;
        default: do_tile< 1>(15, b, tx0, ty0, x, table, out, gbuf, rbuf); break;
    }
}

extern "C" void kernel_launch(void* const* d_in, const int* in_sizes, int n_in,
                              void* d_out, int out_size, void* d_ws, size_t ws_size,
                              hipStream_t stream) {
    const float* x     = (const float*)d_in[0];
    const float* table = (const float*)d_in[1];
    float* out         = (float*)d_out;
    (void)d_ws; (void)ws_size;

    fused_kernel<<<dim3(NLVL * 256 * 8), dim3(256), 0, stream>>>(x, table, out);
}

// Round 5
// 125.929 us; speedup vs baseline: 2.4505x; 1.0827x over previous
//
#include <hip/hip_runtime.h>
#include <stdint.h>

#define NLVL 16
#define TSIZE 16384
#define HW 512

__constant__ int c_n[NLVL] = {16,20,25,32,40,50,64,80,101,128,161,203,256,322,406,512};

__device__ __forceinline__ uint32_t pkmax(uint32_t a, uint32_t b) {
    uint32_t r;
    asm("v_pk_max_u16 %0, %1, %2" : "=v"(r) : "v"(a), "v"(b));
    return r;
}
__device__ __forceinline__ uint4 pk4(uint4 a, uint4 b) {
    return make_uint4(pkmax(a.x,b.x), pkmax(a.y,b.y), pkmax(a.z,b.z), pkmax(a.w,b.w));
}

// One block = one (level, batch, 32x32 output tile).
// gbuf: packed trunc(x*n) region, stride 68 u32 (16B-aligned rows, 2-way banks max).
// rbuf: horizontal window-max BY GRID POSITION (col q = position - cmin), stride 36.
// feat/vm alias gbuf after phase 2 (gbuf dead then).
template<int K>
__device__ __forceinline__ void do_tile(
        const int lvl, const int b, const int tx0, const int ty0,
        const float* __restrict__ x, const float* __restrict__ table,
        float* __restrict__ out,
        uint32_t (&gbuf)[64][68], uint32_t (&rbuf)[64][36]) {
    constexpr int gh = 513 - K;
    constexpr float s = (float)gh * (1.0f / 512.0f);  // exact: gh * 2^-9
    const float nf = (float)c_n[lvl];
    const int tid = threadIdx.x;

    float2 (*feat)[36] = reinterpret_cast<float2(*)[36]>(&gbuf[0][0]);   // 33*36*8 = 9504 B
    uint32_t (*vm)[36] = reinterpret_cast<uint32_t(*)[36]>(
        reinterpret_cast<char*>(&gbuf[0][0]) + 9504);                    // 33*36*4 = 4752 B

    const int gy_base = (int)floorf(((float)ty0 + 0.5f) * s - 0.5f);  // may be -1
    const int gx_base = (int)floorf(((float)tx0 + 0.5f) * s - 0.5f);
    const int rmin = max(gy_base, 0);
    const int rmax = min(gy_base + 32, gh - 1);
    const int cmin = max(gx_base, 0);
    const int cmax = min(gx_base + 32, gh - 1);
    const int Rr = rmax - rmin + K;          // input rows needed (<=64)
    const int Rc = cmax - cmin + K;          // input cols needed (<=64)

    const float* xb0 = x + (size_t)b * 2 * HW * HW;
    const float* xb1 = xb0 + HW * HW;
    const float2* tb = (const float2*)table + (size_t)lvl * TSIZE;

    if constexpr (K == 1) {
        // pooled grid IS trunc(x*n): gather directly by position.
        const int nrm = rmax - rmin, ncm = cmax - cmin;
        for (int p = tid; p < 33 * 33; p += 256) {
            const int i = p / 33, j = p - i * 33;
            const int pr = rmin + min(i, nrm);
            const int pc = cmin + min(j, ncm);
            const uint32_t g0 = (uint32_t)(xb0[pr * HW + pc] * nf);
            const uint32_t g1 = (uint32_t)(xb1[pr * HW + pc] * nf);
            const uint32_t idx = (g0 ^ (g1 * 2654435761u)) & (TSIZE - 1);
            feat[min(i, nrm)][min(j, ncm)] = tb[idx];
        }
        __syncthreads();
    } else {
        // ---- phase 1: load + trunc + pack both channels into u32 ----
        {
            const int lr = tid >> 6, lc = tid & 63;
            if (lc < Rc) {
                const int xx = cmin + lc;
                for (int r = lr; r < Rr; r += 4) {
                    const int yy = rmin + r;
                    const float v0 = xb0[yy * HW + xx];
                    const float v1 = xb1[yy * HW + xx];
                    gbuf[r][lc] = (uint32_t)(v0 * nf) | ((uint32_t)(v1 * nf) << 16);
                }
            }
        }
        __syncthreads();

        // ---- phase 2: horizontal window-max, van Herk in registers ----
        // thread = (row r, group g); group covers 12 positions starting at the
        // 4-aligned base below position max(gx_base + 8g, 0).
        {
            const int r = tid >> 2, g = tid & 3;
            if (r < Rr) {
                const int pb = max(gx_base + g * 8, 0);
                const int a = pb - cmin;                 // >= 0, <= 24
                const int abase = a & ~3;
                constexpr int NCH = (K + 14) >> 2;       // aligned chunks needed
                uint32_t e[NCH * 4];
                const uint4* rp = reinterpret_cast<const uint4*>(&gbuf[r][0]) + (abase >> 2);
#pragma unroll
                for (int c = 0; c < NCH; ++c) {
                    const uint4 q = rp[c];
                    e[4*c] = q.x; e[4*c+1] = q.y; e[4*c+2] = q.z; e[4*c+3] = q.w;
                }
                uint32_t wm[12];
                if constexpr (K >= 12) {
                    uint32_t sfx[12];
                    sfx[11] = e[11];
#pragma unroll
                    for (int d = 10; d >= 0; --d) sfx[d] = pkmax(e[d], sfx[d + 1]);
                    uint32_t run = e[12];
#pragma unroll
                    for (int m = 1; m <= K - 1; ++m) {
                        if (m > 1) run = pkmax(run, e[11 + m]);
                        const int dp = m - (K - 12);     // folds at compile time
                        if (dp >= 0 && dp <= 11) wm[dp] = pkmax(sfx[dp], run);
                    }
                    if constexpr (K == 12) wm[0] = sfx[0];
                } else {
#pragma unroll
                    for (int d = 0; d < 12; ++d) {
                        uint32_t m = e[d];
#pragma unroll
                        for (int t = 1; t < K; ++t) m = pkmax(m, e[d + t]);
                        wm[d] = m;
                    }
                }
                uint4* wr = reinterpret_cast<uint4*>(&rbuf[r][abase]);
                wr[0] = make_uint4(wm[0], wm[1], wm[2], wm[3]);
                wr[1] = make_uint4(wm[4], wm[5], wm[6], wm[7]);
                wr[2] = make_uint4(wm[8], wm[9], wm[10], wm[11]);
            }
        }
        __syncthreads();

        // ---- phase 3a: vertical window-max, van Herk, 3 rows x 4 cols/thread ----
        if (tid < 99) {
            const int qc = tid % 9, ig = tid / 9;        // col quad, row group
            const int a0 = 3 * ig;                       // first output row offset
            const uint4* col = reinterpret_cast<const uint4*>(&rbuf[0][0]) + qc;
            uint4 o0, o1, o2;
            if constexpr (K >= 4) {
                const uint4 e0 = col[(a0 + 0) * 9];
                const uint4 e1 = col[(a0 + 1) * 9];
                const uint4 e2 = col[(a0 + 2) * 9];
                const uint4 s2v = e2;
                const uint4 s1v = pk4(e1, s2v);
                const uint4 s0v = pk4(e0, s1v);
                uint4 run = col[(a0 + 3) * 9];
                if constexpr (K == 4) o0 = pk4(s0v, run);
#pragma unroll
                for (int m = 2; m <= K - 1; ++m) {
                    run = pk4(run, col[(a0 + 2 + m) * 9]);
                    if (m == K - 3) o0 = pk4(s0v, run);
                    if (m == K - 2) o1 = pk4(s1v, run);
                    if (m == K - 1) o2 = pk4(s2v, run);
                }
            } else if constexpr (K == 3) {
                const uint4 e0 = col[a0 * 9], e1 = col[(a0+1) * 9], e2 = col[(a0+2) * 9];
                const uint4 e3 = col[(a0+3) * 9], e4 = col[(a0+4) * 9];
                o0 = pk4(e0, pk4(e1, e2));
                o1 = pk4(e1, pk4(e2, e3));
                o2 = pk4(e2, pk4(e3, e4));
            } else {  // K == 2
                const uint4 e0 = col[a0 * 9], e1 = col[(a0+1) * 9];
                const uint4 e2 = col[(a0+2) * 9], e3 = col[(a0+3) * 9];
                o0 = pk4(e0, e1); o1 = pk4(e1, e2); o2 = pk4(e2, e3);
            }
            *reinterpret_cast<uint4*>(&vm[a0 + 0][qc * 4]) = o0;
            *reinterpret_cast<uint4*>(&vm[a0 + 1][qc * 4]) = o1;
            *reinterpret_cast<uint4*>(&vm[a0 + 2][qc * 4]) = o2;
        }
        __syncthreads();

        // ---- phase 3b: hash + table gather (all threads) ----
        for (int p = tid; p < 33 * 33; p += 256) {
            const int i = p / 33, j = p - i * 33;
            const uint32_t m = vm[i][j];
            const uint32_t idx = ((m & 0xFFFFu) ^ ((m >> 16) * 2654435761u)) & (TSIZE - 1);
            feat[i][j] = tb[idx];
        }
        __syncthreads();
    }

    // ---- phase 4: bilinear interp from LDS + nontemporal store ----
    const int bty = tid >> 5, btx = tid & 31;
    const int xo = tx0 + btx;
    const float sxf = ((float)xo + 0.5f) * s - 0.5f;
    const float fxf = floorf(sxf);
    const float wx = sxf - fxf;
    const int x0i = (int)fxf;
    const int jx0 = min(max(x0i, 0), gh - 1) - cmin;
    const int jx1 = min(max(x0i + 1, 0), gh - 1) - cmin;
    float* ob = out + ((size_t)b * 32 + lvl * 2) * HW * HW;
    for (int oy = bty; oy < 32; oy += 8) {
        const int y = ty0 + oy;
        const float syf = ((float)y + 0.5f) * s - 0.5f;
        const float fyf = floorf(syf);
        const float wy = syf - fyf;
        const int y0i = (int)fyf;
        const int iy0 = min(max(y0i, 0), gh - 1) - rmin;
        const int iy1 = min(max(y0i + 1, 0), gh - 1) - rmin;
        const float2 f00 = feat[iy0][jx0], f01 = feat[iy0][jx1];
        const float2 f10 = feat[iy1][jx0], f11 = feat[iy1][jx1];
        const float w11 = wy * wx;
        const float w10 = wy - w11;
        const float w01 = wx - w11;
        const float w00 = 1.0f - wy - wx + w11;
        const float c0 = f00.x * w00 + f01.x * w01 + f10.x * w10 + f11.x * w11;
        const float c1 = f00.y * w00 + f01.y * w01 + f10.y * w10 + f11.y * w11;
        const size_t o = (size_t)y * HW + xo;
        __builtin_nontemporal_store(c0, &ob[o]);
        __builtin_nontemporal_store(c1, &ob[o + (size_t)HW * HW]);
    }
}

// Grid order: bid = lvl*2048 + tile*8 + b (b fastest -> batch pinned to XCD,
// lvl slowest -> co-resident blocks share code path and x/table locality).
__global__ __launch_bounds__(256) void fused_kernel(
        const float* __restrict__ x, const float* __restrict__ table,
        float* __restrict__ out) {
    __shared__ __align__(16) uint32_t gbuf[64][68];
    __shared__ __align__(16) uint32_t rbuf[64][36];

    const int bid  = blockIdx.x;
    const int b    = bid & 7;
    const int tile = (bid >> 3) & 255;
    const int lvl  = bid >> 11;
    const int tx0  = (tile & 15) * 32;
    const int ty0  = (tile >> 4) * 32;

    switch (lvl) {
        case  0: do_tile<32>( 0, b, tx0, ty0, x, table, out, gbuf, rbuf); break;
        case  1: do_tile<25>( 1, b, tx0, ty0, x, table, out, gbuf, rbuf); break;
        case  2: do_tile<20>( 2, b, tx0, ty0, x, table, out, gbuf, rbuf); break;
        case  3: do_tile<16>( 3, b, tx0, ty0, x, table, out, gbuf, rbuf); break;
        case  4: do_tile<12>( 4, b, tx0, ty0, x, table, out, gbuf, rbuf); break;
        case  5: do_tile<10>( 5, b, tx0, ty0, x, table, out, gbuf, rbuf); break;
        case  6: do_tile< 8>( 6, b, tx0, ty0, x, table, out, gbuf, rbuf); break;
        case  7: do_tile< 6>( 7, b, tx0, ty0, x, table, out, gbuf, rbuf); break;
        case  8: do_tile< 5>( 8, b, tx0, ty0, x, table, out, gbuf, rbuf); break;
        case  9: do_tile< 4>( 9, b, tx0, ty0, x, table, out, gbuf, rbuf); break;
        case 10: do_tile< 3>(10, b, tx0, ty0, x, table, out, gbuf, rbuf); break;
        case 11: do_tile< 2>(11, b, tx0, ty0, x, table, out, gbuf, rbuf); break;
        case 12: do_tile< 2>(12, b, tx0, ty0, x, table, out, gbuf, rbuf); break;
        case 13: do_tile< 1>(13, b, tx0, ty0, x, table, out, gbuf, rbuf); break;
        case 14: do_tile< 1>(14, b, tx0, ty0, x, table, out, gbuf, rbuf); break;
        default: do_tile< 1>(15, b, tx0, ty0, x, table, out, gbuf, rbuf); break;
    }
}

extern "C" void kernel_launch(void* const* d_in, const int* in_sizes, int n_in,
                              void* d_out, int out_size, void* d_ws, size_t ws_size,
                              hipStream_t stream) {
    const float* x     = (const float*)d_in[0];
    const float* table = (const float*)d_in[1];
    float* out         = (float*)d_out;
    (void)d_ws; (void)ws_size;

    fused_kernel<<<dim3(NLVL * 256 * 8), dim3(256), 0, stream>>>(x, table, out);
}